// Round 1
// baseline (3361.639 us; speedup 1.0000x reference)
//
#include <hip/hip_runtime.h>
#include <hip/hip_bf16.h>

#define BB 32
#define SS 512
#define HH 768
#define MAXC 128
#define FEPS 1e-8f

// d_out layout (floats, concatenated tuple in return order)
#define NSCORES (BB*MAXC*MAXC)            // 524288
#define OFF_KVALID (NSCORES)              // 524288
#define OFF_VVALID (OFF_KVALID + BB*MAXC) // 528384
#define OFF_KIDX   (OFF_VVALID + BB*MAXC) // 532480
#define OFF_VIDX   (OFF_KIDX + BB*MAXC)   // 536576

__device__ __forceinline__ unsigned int asc_map(float f) {
    unsigned int u = __float_as_uint(f);
    return (u & 0x80000000u) ? ~u : (u | 0x80000000u);
}

// ---------------- Stage 1: softmax/argmax/conf + stable top-128 ----------------
// grid: 2*B blocks, 512 threads. blockIdx.x: b = x>>1, which = x&1 (0=key,1=val)
__global__ void topk_kernel(const float* __restrict__ logits,
                            const int* __restrict__ mask,
                            float* __restrict__ out,
                            int* __restrict__ kidx, int* __restrict__ vidx) {
    int z = blockIdx.x;
    int b = z >> 1;
    int which = z & 1;
    int t = threadIdx.x; // sequence position 0..511
    __shared__ unsigned long long keys[SS];

    const float* l = logits + ((size_t)b * SS + t) * 3;
    float l0 = l[0], l1 = l[1], l2 = l[2];
    int pred = 0; float best = l0;
    if (l1 > best) { best = l1; pred = 1; }
    if (l2 > best) { pred = 2; }
    float m = fmaxf(l0, fmaxf(l1, l2));
    float e0 = expf(l0 - m), e1 = expf(l1 - m), e2 = expf(l2 - m);
    float denom = e0 + e1 + e2;
    float p = (which == 0 ? e1 : e2) / denom;
    int want = which + 1;
    bool ok = (pred == want) && (mask[b * SS + t] == 1);
    float conf = ok ? p : -__builtin_inff();

    unsigned int d = ~asc_map(conf); // descending order map
    keys[t] = ((unsigned long long)d << 32) | (unsigned int)t;
    __syncthreads();

    // bitonic sort ascending (desc conf, then ascending idx for ties)
    for (int k = 2; k <= SS; k <<= 1) {
        for (int j = k >> 1; j > 0; j >>= 1) {
            int ixj = t ^ j;
            if (ixj > t) {
                unsigned long long a = keys[t], c = keys[ixj];
                bool up = ((t & k) == 0);
                bool sw = up ? (a > c) : (a < c);
                if (sw) { keys[t] = c; keys[ixj] = a; }
            }
            __syncthreads();
        }
    }

    if (t < MAXC) {
        unsigned long long kk = keys[t];
        int idx = (int)(kk & 0xFFFFFFFFu);
        bool valid = ((unsigned int)(kk >> 32)) != 0xFF800000u; // != map(-inf)
        if (which == 0) {
            kidx[b * MAXC + t] = idx;
            out[OFF_KVALID + b * MAXC + t] = valid ? 1.0f : 0.0f;
            out[OFF_KIDX + b * MAXC + t] = (float)idx;
        } else {
            vidx[b * MAXC + t] = idx;
            out[OFF_VVALID + b * MAXC + t] = valid ? 1.0f : 0.0f;
            out[OFF_VIDX + b * MAXC + t] = (float)idx;
        }
    }
}

// ---------------- Stage 2/3a: (optionally row-gathered) GEMM ----------------
// C[m][n] = sum_k A[arow(m)][k] * W[k][n] (+ bias[n])
// BM=BN=64, BK=16, 256 threads, 4x4 micro-tile. N=K=768, M=4096.
__global__ void gemm_rowgather(const float* __restrict__ A,
                               const float* __restrict__ W,
                               const float* __restrict__ bias,
                               float* __restrict__ C,
                               const int* __restrict__ idx) {
    __shared__ __align__(16) float As[16 * 68]; // [k][m], stride 68
    __shared__ __align__(16) float Bs[16 * 68]; // [k][n], stride 68
    const int K = HH, N = HH;
    int t = threadIdx.x;
    int tm = t >> 4, tn = t & 15;
    int m0 = blockIdx.y * 64;
    int n0 = blockIdx.x * 64;

    int lrow = t >> 2, lkq = t & 3;   // A-load: 64 rows x 4 float4
    int gm = m0 + lrow;
    long arow;
    if (idx) {
        int b = gm >> 7;
        arow = (long)b * SS + idx[gm];
    } else {
        arow = gm;
    }
    const float* Aptr = A + arow * (long)K + lkq * 4;
    int bkk = t >> 4, bnq = t & 15;   // B-load: 16 rows x 16 float4
    const float* Wptr = W + (long)bkk * N + n0 + bnq * 4;

    float acc[4][4];
    #pragma unroll
    for (int i = 0; i < 4; ++i)
        #pragma unroll
        for (int j = 0; j < 4; ++j) acc[i][j] = 0.0f;

    for (int k0 = 0; k0 < K; k0 += 16) {
        float4 av = *(const float4*)(Aptr + k0);
        As[(lkq * 4 + 0) * 68 + lrow] = av.x;
        As[(lkq * 4 + 1) * 68 + lrow] = av.y;
        As[(lkq * 4 + 2) * 68 + lrow] = av.z;
        As[(lkq * 4 + 3) * 68 + lrow] = av.w;
        float4 bv = *(const float4*)(Wptr + (long)k0 * N);
        *(float4*)&Bs[bkk * 68 + bnq * 4] = bv;
        __syncthreads();
        #pragma unroll
        for (int kk = 0; kk < 16; ++kk) {
            float4 a4 = *(const float4*)&As[kk * 68 + tm * 4];
            float4 b4 = *(const float4*)&Bs[kk * 68 + tn * 4];
            float a[4] = {a4.x, a4.y, a4.z, a4.w};
            float bb2[4] = {b4.x, b4.y, b4.z, b4.w};
            #pragma unroll
            for (int i = 0; i < 4; ++i)
                #pragma unroll
                for (int j = 0; j < 4; ++j) acc[i][j] += a[i] * bb2[j];
        }
        __syncthreads();
    }

    #pragma unroll
    for (int i = 0; i < 4; ++i) {
        #pragma unroll
        for (int j = 0; j < 4; ++j) {
            int n = n0 + tn * 4 + j;
            float v = acc[i][j];
            if (bias) v += bias[n];
            C[(long)(m0 + tm * 4 + i) * N + n] = v;
        }
    }
}

// ---------------- Stage 3b: biaffine = tmp . val_reps^T + bbil ----------------
// per batch: M=N=128, K=768. grid (2,2,B), BM=BN=64, BK=16.
__global__ void biaffine_kernel(const float* __restrict__ TA,  // [B,128,768]
                                const float* __restrict__ VB,  // [B,128,768]
                                const float* __restrict__ bbil,
                                float* __restrict__ biaf) {    // [B,128,128]
    __shared__ __align__(16) float As[16 * 68];
    __shared__ __align__(16) float Bs[16 * 68];
    int b = blockIdx.z;
    int m0 = blockIdx.y * 64, n0 = blockIdx.x * 64;
    int t = threadIdx.x;
    int tm = t >> 4, tn = t & 15;
    int lrow = t >> 2, lkq = t & 3;
    const float* Ap = TA + ((long)b * MAXC + m0 + lrow) * HH + lkq * 4;
    const float* Bp = VB + ((long)b * MAXC + n0 + lrow) * HH + lkq * 4;

    float acc[4][4];
    #pragma unroll
    for (int i = 0; i < 4; ++i)
        #pragma unroll
        for (int j = 0; j < 4; ++j) acc[i][j] = 0.0f;

    for (int k0 = 0; k0 < HH; k0 += 16) {
        float4 av = *(const float4*)(Ap + k0);
        float4 bv = *(const float4*)(Bp + k0);
        As[(lkq * 4 + 0) * 68 + lrow] = av.x;
        As[(lkq * 4 + 1) * 68 + lrow] = av.y;
        As[(lkq * 4 + 2) * 68 + lrow] = av.z;
        As[(lkq * 4 + 3) * 68 + lrow] = av.w;
        Bs[(lkq * 4 + 0) * 68 + lrow] = bv.x;
        Bs[(lkq * 4 + 1) * 68 + lrow] = bv.y;
        Bs[(lkq * 4 + 2) * 68 + lrow] = bv.z;
        Bs[(lkq * 4 + 3) * 68 + lrow] = bv.w;
        __syncthreads();
        #pragma unroll
        for (int kk = 0; kk < 16; ++kk) {
            float4 a4 = *(const float4*)&As[kk * 68 + tm * 4];
            float4 b4 = *(const float4*)&Bs[kk * 68 + tn * 4];
            float a[4] = {a4.x, a4.y, a4.z, a4.w};
            float bb2[4] = {b4.x, b4.y, b4.z, b4.w};
            #pragma unroll
            for (int i = 0; i < 4; ++i)
                #pragma unroll
                for (int j = 0; j < 4; ++j) acc[i][j] += a[i] * bb2[j];
        }
        __syncthreads();
    }

    float bb = bbil[0];
    #pragma unroll
    for (int i = 0; i < 4; ++i)
        #pragma unroll
        for (int j = 0; j < 4; ++j)
            biaf[((long)b * MAXC + m0 + tm * 4 + i) * MAXC + n0 + tn * 4 + j] =
                acc[i][j] + bb;
}

// ---------------- Stage 4: spatial features + MLPs + fusion head ----------------
// grid (8,8,B), block (16,16): one thread per (k,v) pair in a 16x16 tile.
__global__ void spatial_kernel(const float* __restrict__ bboxes,
                               const int* __restrict__ kidx,
                               const int* __restrict__ vidx,
                               const float* __restrict__ biaf,
                               const float* __restrict__ Ws1, const float* __restrict__ bs1,
                               const float* __restrict__ Ws2, const float* __restrict__ bs2,
                               const float* __restrict__ Wf1, const float* __restrict__ bf1,
                               const float* __restrict__ Wf2, const float* __restrict__ bf2,
                               float* __restrict__ out) {
    __shared__ float sW1[8 * 64], sb1[64], sW2[64 * 32], sb2[32];
    __shared__ float sF1[33 * 16], sf1b[16], sF2[16];
    __shared__ float sbf2;
    __shared__ float kb[16][4], vb[16][4];

    int b = blockIdx.z, kt = blockIdx.y, vt = blockIdx.x;
    int t = threadIdx.y * 16 + threadIdx.x;

    for (int i = t; i < 512; i += 256) sW1[i] = Ws1[i];
    for (int i = t; i < 2048; i += 256) sW2[i] = Ws2[i];
    for (int i = t; i < 528; i += 256) sF1[i] = Wf1[i];
    if (t < 64) sb1[t] = bs1[t];
    if (t >= 64 && t < 96) sb2[t - 64] = bs2[t - 64];
    if (t >= 96 && t < 112) sf1b[t - 96] = bf1[t - 96];
    if (t >= 112 && t < 128) sF2[t - 112] = Wf2[t - 112];
    if (t == 128) sbf2 = bf2[0];
    if (t < 64) {
        int r = t >> 2, c = t & 3;
        kb[r][c] = bboxes[((long)b * SS + kidx[b * MAXC + kt * 16 + r]) * 4 + c];
    } else if (t < 128 + 64 && t >= 128) {
        int q = t - 128; int r = q >> 2, c = q & 3;
        vb[r][c] = bboxes[((long)b * SS + vidx[b * MAXC + vt * 16 + r]) * 4 + c];
    }
    __syncthreads();

    int kr = threadIdx.y, vc = threadIdx.x;
    float k1 = kb[kr][0], k2 = kb[kr][1], k3 = kb[kr][2], k4 = kb[kr][3];
    float v1 = vb[vc][0], v2 = vb[vc][1], v3 = vb[vc][2], v4 = vb[vc][3];
    float kcx = (k1 + k3) * 0.5f, kcy = (k2 + k4) * 0.5f;
    float vcx = (v1 + v3) * 0.5f, vcy = (v2 + v4) * 0.5f;
    float dx = vcx - kcx, dy = vcy - kcy;
    float dist = sqrtf(dx * dx + dy * dy + FEPS);
    float angle = atan2f(dy, dx);
    float kh = k4 - k2, kw = k3 - k1, vh = v4 - v2, vw = v3 - v1;
    float h_ov = fmaxf(fminf(k4, v4) - fmaxf(k2, v2), 0.0f);
    float h_align = h_ov / (fminf(kh, vh) + FEPS);
    float v_ov = fmaxf(fminf(k3, v3) - fmaxf(k1, v1), 0.0f);
    float v_align = v_ov / (fminf(kw, vw) + FEPS);
    float area = (vh * vw) / (kh * kw + FEPS);
    float aspect = (vw / (vh + FEPS)) / (kw / (kh + FEPS));
    float sf[8] = {dx, dy, dist, angle, h_align, v_align, area, aspect};

    float h1[64];
    #pragma unroll
    for (int j = 0; j < 64; ++j) {
        float a = sb1[j];
        #pragma unroll
        for (int i = 0; i < 8; ++i) a += sf[i] * sW1[i * 64 + j];
        h1[j] = fmaxf(a, 0.0f);
    }
    float h2[32];
    #pragma unroll
    for (int j = 0; j < 32; ++j) {
        float a = sb2[j];
        #pragma unroll
        for (int i = 0; i < 64; ++i) a += h1[i] * sW2[i * 32 + j];
        h2[j] = a;
    }

    int k = kt * 16 + kr, v = vt * 16 + vc;
    float bia = biaf[((long)b * MAXC + k) * MAXC + v];
    float sc = sbf2;
    #pragma unroll
    for (int j = 0; j < 16; ++j) {
        float f = sf1b[j] + bia * sF1[0 * 16 + j];
        #pragma unroll
        for (int i = 0; i < 32; ++i) f += h2[i] * sF1[(i + 1) * 16 + j];
        f = fmaxf(f, 0.0f);
        sc += f * sF2[j];
    }
    out[((long)b * MAXC + k) * MAXC + v] = sc;
}

extern "C" void kernel_launch(void* const* d_in, const int* in_sizes, int n_in,
                              void* d_out, int out_size, void* d_ws, size_t ws_size,
                              hipStream_t stream) {
    const float* seq    = (const float*)d_in[0];
    const float* logits = (const float*)d_in[1];
    const float* bboxes = (const float*)d_in[2];
    const int*   mask   = (const int*)d_in[3];
    const float* Wk  = (const float*)d_in[4];
    const float* bk  = (const float*)d_in[5];
    const float* Wv  = (const float*)d_in[6];
    const float* bv  = (const float*)d_in[7];
    const float* Wbil = (const float*)d_in[8];
    const float* bbil = (const float*)d_in[9];
    const float* Ws1 = (const float*)d_in[10];
    const float* bs1 = (const float*)d_in[11];
    const float* Ws2 = (const float*)d_in[12];
    const float* bs2 = (const float*)d_in[13];
    const float* Wf1 = (const float*)d_in[14];
    const float* bf1 = (const float*)d_in[15];
    const float* Wf2 = (const float*)d_in[16];
    const float* bf2 = (const float*)d_in[17];
    float* out = (float*)d_out;

    // workspace layout
    int* kidx = (int*)d_ws;
    int* vidx = kidx + BB * MAXC;
    float* key_reps = (float*)(vidx + BB * MAXC);            // [4096,768]
    float* val_reps = key_reps + (size_t)BB * MAXC * HH;     // [4096,768]
    float* tmpb     = val_reps + (size_t)BB * MAXC * HH;     // [4096,768]
    float* biaf     = tmpb     + (size_t)BB * MAXC * HH;     // [32,128,128]

    topk_kernel<<<2 * BB, SS, 0, stream>>>(logits, mask, out, kidx, vidx);
    gemm_rowgather<<<dim3(12, 64), 256, 0, stream>>>(seq, Wk, bk, key_reps, kidx);
    gemm_rowgather<<<dim3(12, 64), 256, 0, stream>>>(seq, Wv, bv, val_reps, vidx);
    gemm_rowgather<<<dim3(12, 64), 256, 0, stream>>>(key_reps, Wbil, nullptr, tmpb, nullptr);
    biaffine_kernel<<<dim3(2, 2, BB), 256, 0, stream>>>(tmpb, val_reps, bbil, biaf);
    spatial_kernel<<<dim3(8, 8, BB), dim3(16, 16), 0, stream>>>(
        bboxes, kidx, vidx, biaf, Ws1, bs1, Ws2, bs2, Wf1, bf1, Wf2, bf2, out);
}

// Round 5
// 449.145 us; speedup vs baseline: 7.4845x; 7.4845x over previous
//
#include <hip/hip_runtime.h>
#include <hip/hip_bf16.h>

#define BB 32
#define SS 512
#define HH 768
#define MAXC 128
#define FEPS 1e-8f

// d_out layout (floats, concatenated tuple in return order)
#define NSCORES (BB*MAXC*MAXC)            // 524288
#define OFF_KVALID (NSCORES)              // 524288
#define OFF_VVALID (OFF_KVALID + BB*MAXC) // 528384
#define OFF_KIDX   (OFF_VVALID + BB*MAXC) // 532480
#define OFF_VIDX   (OFF_KIDX + BB*MAXC)   // 536576

__device__ __forceinline__ unsigned int asc_map(float f) {
    unsigned int u = __float_as_uint(f);
    return (u & 0x80000000u) ? ~u : (u | 0x80000000u);
}

// ---------------- Stage 1: softmax/argmax/conf + stable top-128 ----------------
__global__ void topk_kernel(const float* __restrict__ logits,
                            const int* __restrict__ mask,
                            float* __restrict__ out,
                            int* __restrict__ kidx, int* __restrict__ vidx) {
    int z = blockIdx.x;
    int b = z >> 1;
    int which = z & 1;
    int t = threadIdx.x; // sequence position 0..511
    __shared__ unsigned long long keys[SS];

    const float* l = logits + ((size_t)b * SS + t) * 3;
    float l0 = l[0], l1 = l[1], l2 = l[2];
    int pred = 0; float best = l0;
    if (l1 > best) { best = l1; pred = 1; }
    if (l2 > best) { pred = 2; }
    float m = fmaxf(l0, fmaxf(l1, l2));
    float e0 = expf(l0 - m), e1 = expf(l1 - m), e2 = expf(l2 - m);
    float denom = e0 + e1 + e2;
    float p = (which == 0 ? e1 : e2) / denom;
    int want = which + 1;
    bool ok = (pred == want) && (mask[b * SS + t] == 1);
    float conf = ok ? p : -__builtin_inff();

    unsigned int d = ~asc_map(conf); // descending order map
    keys[t] = ((unsigned long long)d << 32) | (unsigned int)t;
    __syncthreads();

    for (int k = 2; k <= SS; k <<= 1) {
        for (int j = k >> 1; j > 0; j >>= 1) {
            int ixj = t ^ j;
            if (ixj > t) {
                unsigned long long a = keys[t], c = keys[ixj];
                bool up = ((t & k) == 0);
                bool sw = up ? (a > c) : (a < c);
                if (sw) { keys[t] = c; keys[ixj] = a; }
            }
            __syncthreads();
        }
    }

    if (t < MAXC) {
        unsigned long long kk = keys[t];
        int idx = (int)(kk & 0xFFFFFFFFu);
        bool valid = ((unsigned int)(kk >> 32)) != 0xFF800000u; // != map(-inf)
        if (which == 0) {
            kidx[b * MAXC + t] = idx;
            out[OFF_KVALID + b * MAXC + t] = valid ? 1.0f : 0.0f;
            out[OFF_KIDX + b * MAXC + t] = (float)idx;
        } else {
            vidx[b * MAXC + t] = idx;
            out[OFF_VVALID + b * MAXC + t] = valid ? 1.0f : 0.0f;
            out[OFF_VIDX + b * MAXC + t] = (float)idx;
        }
    }
}

// ---------------- Stage 2/3a: (optionally row-gathered) GEMM ----------------
__global__ void gemm_rowgather(const float* __restrict__ A,
                               const float* __restrict__ W,
                               const float* __restrict__ bias,
                               float* __restrict__ C,
                               const int* __restrict__ idx) {
    __shared__ __align__(16) float As[16 * 68]; // [k][m], stride 68
    __shared__ __align__(16) float Bs[16 * 68]; // [k][n], stride 68
    const int K = HH, N = HH;
    int t = threadIdx.x;
    int tm = t >> 4, tn = t & 15;
    int m0 = blockIdx.y * 64;
    int n0 = blockIdx.x * 64;

    int lrow = t >> 2, lkq = t & 3;   // A-load: 64 rows x 4 float4
    int gm = m0 + lrow;
    long arow;
    if (idx) {
        int b = gm >> 7;
        arow = (long)b * SS + idx[gm];
    } else {
        arow = gm;
    }
    const float* Aptr = A + arow * (long)K + lkq * 4;
    int bkk = t >> 4, bnq = t & 15;   // B-load: 16 rows x 16 float4
    const float* Wptr = W + (long)bkk * N + n0 + bnq * 4;

    float acc[4][4];
    #pragma unroll
    for (int i = 0; i < 4; ++i)
        #pragma unroll
        for (int j = 0; j < 4; ++j) acc[i][j] = 0.0f;

    for (int k0 = 0; k0 < K; k0 += 16) {
        float4 av = *(const float4*)(Aptr + k0);
        As[(lkq * 4 + 0) * 68 + lrow] = av.x;
        As[(lkq * 4 + 1) * 68 + lrow] = av.y;
        As[(lkq * 4 + 2) * 68 + lrow] = av.z;
        As[(lkq * 4 + 3) * 68 + lrow] = av.w;
        float4 bv = *(const float4*)(Wptr + (long)k0 * N);
        *(float4*)&Bs[bkk * 68 + bnq * 4] = bv;
        __syncthreads();
        #pragma unroll
        for (int kk = 0; kk < 16; ++kk) {
            float4 a4 = *(const float4*)&As[kk * 68 + tm * 4];
            float4 b4 = *(const float4*)&Bs[kk * 68 + tn * 4];
            float a[4] = {a4.x, a4.y, a4.z, a4.w};
            float bb2[4] = {b4.x, b4.y, b4.z, b4.w};
            #pragma unroll
            for (int i = 0; i < 4; ++i)
                #pragma unroll
                for (int j = 0; j < 4; ++j) acc[i][j] += a[i] * bb2[j];
        }
        __syncthreads();
    }

    #pragma unroll
    for (int i = 0; i < 4; ++i) {
        #pragma unroll
        for (int j = 0; j < 4; ++j) {
            int n = n0 + tn * 4 + j;
            float v = acc[i][j];
            if (bias) v += bias[n];
            C[(long)(m0 + tm * 4 + i) * N + n] = v;
        }
    }
}

// ---------------- Stage 3b: biaffine = tmp . val_reps^T + bbil ----------------
__global__ void biaffine_kernel(const float* __restrict__ TA,  // [B,128,768]
                                const float* __restrict__ VB,  // [B,128,768]
                                const float* __restrict__ bbil,
                                float* __restrict__ biaf) {    // [B,128,128]
    __shared__ __align__(16) float As[16 * 68];
    __shared__ __align__(16) float Bs[16 * 68];
    int b = blockIdx.z;
    int m0 = blockIdx.y * 64, n0 = blockIdx.x * 64;
    int t = threadIdx.x;
    int tm = t >> 4, tn = t & 15;
    int lrow = t >> 2, lkq = t & 3;
    const float* Ap = TA + ((long)b * MAXC + m0 + lrow) * HH + lkq * 4;
    const float* Bp = VB + ((long)b * MAXC + n0 + lrow) * HH + lkq * 4;

    float acc[4][4];
    #pragma unroll
    for (int i = 0; i < 4; ++i)
        #pragma unroll
        for (int j = 0; j < 4; ++j) acc[i][j] = 0.0f;

    for (int k0 = 0; k0 < HH; k0 += 16) {
        float4 av = *(const float4*)(Ap + k0);
        float4 bv = *(const float4*)(Bp + k0);
        As[(lkq * 4 + 0) * 68 + lrow] = av.x;
        As[(lkq * 4 + 1) * 68 + lrow] = av.y;
        As[(lkq * 4 + 2) * 68 + lrow] = av.z;
        As[(lkq * 4 + 3) * 68 + lrow] = av.w;
        Bs[(lkq * 4 + 0) * 68 + lrow] = bv.x;
        Bs[(lkq * 4 + 1) * 68 + lrow] = bv.y;
        Bs[(lkq * 4 + 2) * 68 + lrow] = bv.z;
        Bs[(lkq * 4 + 3) * 68 + lrow] = bv.w;
        __syncthreads();
        #pragma unroll
        for (int kk = 0; kk < 16; ++kk) {
            float4 a4 = *(const float4*)&As[kk * 68 + tm * 4];
            float4 b4 = *(const float4*)&Bs[kk * 68 + tn * 4];
            float a[4] = {a4.x, a4.y, a4.z, a4.w};
            float bb2[4] = {b4.x, b4.y, b4.z, b4.w};
            #pragma unroll
            for (int i = 0; i < 4; ++i)
                #pragma unroll
                for (int j = 0; j < 4; ++j) acc[i][j] += a[i] * bb2[j];
        }
        __syncthreads();
    }

    float bb = bbil[0];
    #pragma unroll
    for (int i = 0; i < 4; ++i)
        #pragma unroll
        for (int j = 0; j < 4; ++j)
            biaf[((long)b * MAXC + m0 + tm * 4 + i) * MAXC + n0 + tn * 4 + j] =
                acc[i][j] + bb;
}

// ---------------- Stage 4: spatial features + MLPs + fusion head ----------------
// Fused-layer form: h2[j] += relu(h1_i)*W2[i][j] as h1_i is produced, so the
// only live state is sf[8]+h2[32] (~48 VGPRs) -> no scratch spill.
__global__ void spatial_kernel(const float* __restrict__ bboxes,
                               const int* __restrict__ kidx,
                               const int* __restrict__ vidx,
                               const float* __restrict__ biaf,
                               const float* __restrict__ Ws1, const float* __restrict__ bs1,
                               const float* __restrict__ Ws2, const float* __restrict__ bs2,
                               const float* __restrict__ Wf1, const float* __restrict__ bf1,
                               const float* __restrict__ Wf2, const float* __restrict__ bf2,
                               float* __restrict__ out) {
    __shared__ float sW1[8 * 64], sb1[64], sW2[64 * 32], sb2[32];
    __shared__ float sF1[33 * 16], sf1b[16], sF2[16];
    __shared__ float sbf2;
    __shared__ float kb[16][4], vb[16][4];

    int b = blockIdx.z, kt = blockIdx.y, vt = blockIdx.x;
    int t = threadIdx.y * 16 + threadIdx.x;

    for (int i = t; i < 512; i += 256) sW1[i] = Ws1[i];
    for (int i = t; i < 2048; i += 256) sW2[i] = Ws2[i];
    for (int i = t; i < 528; i += 256) sF1[i] = Wf1[i];
    if (t < 64) sb1[t] = bs1[t];
    if (t >= 64 && t < 96) sb2[t - 64] = bs2[t - 64];
    if (t >= 96 && t < 112) sf1b[t - 96] = bf1[t - 96];
    if (t >= 112 && t < 128) sF2[t - 112] = Wf2[t - 112];
    if (t == 128) sbf2 = bf2[0];
    if (t < 64) {
        int r = t >> 2, c = t & 3;
        kb[r][c] = bboxes[((long)b * SS + kidx[b * MAXC + kt * 16 + r]) * 4 + c];
    } else if (t < 192 && t >= 128) {
        int q = t - 128; int r = q >> 2, c = q & 3;
        vb[r][c] = bboxes[((long)b * SS + vidx[b * MAXC + vt * 16 + r]) * 4 + c];
    }
    __syncthreads();

    int kr = threadIdx.y, vc = threadIdx.x;
    float k1 = kb[kr][0], k2 = kb[kr][1], k3 = kb[kr][2], k4 = kb[kr][3];
    float v1 = vb[vc][0], v2 = vb[vc][1], v3 = vb[vc][2], v4 = vb[vc][3];
    float kcx = (k1 + k3) * 0.5f, kcy = (k2 + k4) * 0.5f;
    float vcx = (v1 + v3) * 0.5f, vcy = (v2 + v4) * 0.5f;
    float dx = vcx - kcx, dy = vcy - kcy;
    float dist = sqrtf(dx * dx + dy * dy + FEPS);
    float angle = atan2f(dy, dx);
    float kh = k4 - k2, kw = k3 - k1, vh = v4 - v2, vw = v3 - v1;
    float h_ov = fmaxf(fminf(k4, v4) - fmaxf(k2, v2), 0.0f);
    float h_align = h_ov / (fminf(kh, vh) + FEPS);
    float v_ov = fmaxf(fminf(k3, v3) - fmaxf(k1, v1), 0.0f);
    float v_align = v_ov / (fminf(kw, vw) + FEPS);
    float area = (vh * vw) / (kh * kw + FEPS);
    float aspect = (vw / (vh + FEPS)) / (kw / (kh + FEPS));
    float sf[8] = {dx, dy, dist, angle, h_align, v_align, area, aspect};

    // Fused MLP: layer1 row i -> immediately accumulated into h2[32]
    float h2[32];
    #pragma unroll
    for (int j = 0; j < 32; ++j) h2[j] = sb2[j];
    #pragma unroll 4
    for (int i = 0; i < 64; ++i) {
        float a = sb1[i];
        #pragma unroll
        for (int q = 0; q < 8; ++q) a += sf[q] * sW1[q * 64 + i];
        a = fmaxf(a, 0.0f);
        #pragma unroll
        for (int j = 0; j < 32; ++j) h2[j] += a * sW2[i * 32 + j];
    }

    int k = kt * 16 + kr, v = vt * 16 + vc;
    float bia = biaf[((long)b * MAXC + k) * MAXC + v];
    float sc = sbf2;
    #pragma unroll
    for (int j = 0; j < 16; ++j) {
        float f = sf1b[j] + bia * sF1[0 * 16 + j];
        #pragma unroll
        for (int i = 0; i < 32; ++i) f += h2[i] * sF1[(i + 1) * 16 + j];
        f = fmaxf(f, 0.0f);
        sc += f * sF2[j];
    }
    out[((long)b * MAXC + k) * MAXC + v] = sc;
}

extern "C" void kernel_launch(void* const* d_in, const int* in_sizes, int n_in,
                              void* d_out, int out_size, void* d_ws, size_t ws_size,
                              hipStream_t stream) {
    const float* seq    = (const float*)d_in[0];
    const float* logits = (const float*)d_in[1];
    const float* bboxes = (const float*)d_in[2];
    const int*   mask   = (const int*)d_in[3];
    const float* Wk  = (const float*)d_in[4];
    const float* bk  = (const float*)d_in[5];
    const float* Wv  = (const float*)d_in[6];
    const float* bv  = (const float*)d_in[7];
    const float* Wbil = (const float*)d_in[8];
    const float* bbil = (const float*)d_in[9];
    const float* Ws1 = (const float*)d_in[10];
    const float* bs1 = (const float*)d_in[11];
    const float* Ws2 = (const float*)d_in[12];
    const float* bs2 = (const float*)d_in[13];
    const float* Wf1 = (const float*)d_in[14];
    const float* bf1 = (const float*)d_in[15];
    const float* Wf2 = (const float*)d_in[16];
    const float* bf2 = (const float*)d_in[17];
    float* out = (float*)d_out;

    // workspace layout
    int* kidx = (int*)d_ws;
    int* vidx = kidx + BB * MAXC;
    float* key_reps = (float*)(vidx + BB * MAXC);            // [4096,768]
    float* val_reps = key_reps + (size_t)BB * MAXC * HH;     // [4096,768]
    float* tmpb     = val_reps + (size_t)BB * MAXC * HH;     // [4096,768]
    float* biaf     = tmpb     + (size_t)BB * MAXC * HH;     // [32,128,128]

    topk_kernel<<<2 * BB, SS, 0, stream>>>(logits, mask, out, kidx, vidx);
    gemm_rowgather<<<dim3(12, 64), 256, 0, stream>>>(seq, Wk, bk, key_reps, kidx);
    gemm_rowgather<<<dim3(12, 64), 256, 0, stream>>>(seq, Wv, bv, val_reps, vidx);
    gemm_rowgather<<<dim3(12, 64), 256, 0, stream>>>(key_reps, Wbil, nullptr, tmpb, nullptr);
    biaffine_kernel<<<dim3(2, 2, BB), 256, 0, stream>>>(tmpb, val_reps, bbil, biaf);
    spatial_kernel<<<dim3(8, 8, BB), dim3(16, 16), 0, stream>>>(
        bboxes, kidx, vidx, biaf, Ws1, bs1, Ws2, bs2, Wf1, bf1, Wf2, bf2, out);
}